// Round 8
// baseline (1878.843 us; speedup 1.0000x reference)
//
#include <hip/hip_runtime.h>
#include <hip/hip_bf16.h>

#define T_SEQ 512
#define BATCH 256
#define HID   1024
#define EMBD  256
#define NCLS  10

typedef __bf16 bf16x8 __attribute__((ext_vector_type(8)));
typedef float  floatx16 __attribute__((ext_vector_type(16)));
typedef float  floatx2 __attribute__((ext_vector_type(2)));
typedef unsigned short ushortx8 __attribute__((ext_vector_type(8)));

__device__ __forceinline__ unsigned int f2bf(float f) {
    unsigned int u = __builtin_bit_cast(unsigned int, f);
    u += 0x7fffu + ((u >> 16) & 1u);
    return u >> 16;
}
__device__ __forceinline__ float sig_fast(float x) {
    return __builtin_amdgcn_rcpf(1.0f + __expf(-x));
}
__device__ __forceinline__ float tanh_fast(float x) {
    return 1.0f - 2.0f * __builtin_amdgcn_rcpf(1.0f + __expf(2.0f * x));
}

// -------------------- prep: XW[tok][gate][n] = emb[tok] @ Wx_gate + b_gate ---
__global__ void prep_xw_kernel(const float* __restrict__ emb,
                               const float* __restrict__ wgx, const float* __restrict__ wix,
                               const float* __restrict__ wfx, const float* __restrict__ wox,
                               const float* __restrict__ bg,  const float* __restrict__ bi,
                               const float* __restrict__ bf,  const float* __restrict__ bo,
                               float* __restrict__ XW) {
    int gid = blockIdx.x * blockDim.x + threadIdx.x;     // 3*4*1024 = 12288
    if (gid >= 3 * 4 * HID) return;
    int tok  = gid >> 12;
    int gate = (gid >> 10) & 3;
    int n    = gid & 1023;
    const float* W = gate == 0 ? wgx : gate == 1 ? wix : gate == 2 ? wfx : wox;
    const float* B = gate == 0 ? bg  : gate == 1 ? bi  : gate == 2 ? bf  : bo;
    float acc = B[n];
    const float* e = emb + tok * EMBD;
    for (int k = 0; k < EMBD; ++k) acc += e[k] * W[k * HID + n];
    XW[gid] = acc;
}

// ---- prep: Wt in 32x32x16 MFMA B-fragment order, K-quarter granularity ----
// frag = ((w*4+g)*4+q)*16 + i ; Wt[frag*512 + lane*8 + e]
//   = bf16( W_g[k = q*256 + i*16 + (lane>>5)*8 + e][j = w*32 + (lane&31)] )
__global__ void prep_w_kernel(const float* __restrict__ wgh, const float* __restrict__ wih,
                              const float* __restrict__ wfh, const float* __restrict__ woh,
                              unsigned short* __restrict__ Wt) {
    int bid = blockIdx.x;                 // 8192 = g(2b) q(2b) i(4b) w(5b)
    int w   = bid & 31;
    int i   = (bid >> 5) & 15;
    int q   = (bid >> 9) & 3;
    int g   = bid >> 11;
    const float* W = g == 0 ? wgh : g == 1 ? wih : g == 2 ? wfh : woh;
    int lane = threadIdx.x;               // 64
    int j    = w * 32 + (lane & 31);
    int k0   = q * 256 + i * 16 + (lane >> 5) * 8;
    ushortx8 o8;
    #pragma unroll
    for (int e = 0; e < 8; ++e) o8[e] = (unsigned short)f2bf(W[(k0 + e) * HID + j]);
    int frag = ((w * 4 + g) * 4 + q) * 16 + i;
    *(ushortx8*)&Wt[frag * 512 + lane * 8] = o8;
}

// -------------------- persistent recurrent kernel ---------------------------
// 256 WGs x 512 threads. grp = blockIdx%8 owns 32 batch rows; w = blockIdx/8
// owns 32 hidden cols. Wave wv: K-quarter qv = wv>>1 (256 k), gate-pair
// pv = wv&1 (gates 2pv, 2pv+1). One A-load feeds two MFMAs -> LDS A-read
// traffic halved vs R7 (128 KB/step/CU). Waves wait only on their quarter's 8
// producers; team-of-2 stages its 16 KB slice behind an LDS team barrier (no
// WG barrier between stage and GEMM). Exchange protocol = R7 (local XCD L2
// write-back when co-resident, verified via HW_REG_XCC_ID; system fallback).
__global__ __launch_bounds__(512, 2)
void lstm_kernel(const int* __restrict__ x, const float* __restrict__ XW,
                 const unsigned short* __restrict__ Wt,
                 unsigned int* __restrict__ hbuf32, int* __restrict__ flags,
                 int* __restrict__ xflag) {
    __shared__ __align__(16) unsigned short hs[4 * 8448]; // 4 slices [32][264]  (67584 B)
    __shared__ float gbuf[16 * 1152];          // [gate][q][row][col+pad]        (73728 B)
    __shared__ float xwl[384];                 // [tok][gate][32 cols]           (1536 B)
    __shared__ unsigned char xtokp[4096];      // tokens 2-bit packed            (4096 B)
    __shared__ int qctr[4];
    __shared__ int use_local_sh;

    const int tid  = threadIdx.x;
    const int grp  = blockIdx.x & 7;
    const int w    = blockIdx.x >> 3;
    const int wv   = tid >> 6;
    const int qv   = wv >> 1;                  // K-quarter
    const int pv   = wv & 1;                   // gate-pair
    const int lane = tid & 63;
    const int m32  = lane & 31;
    const int hv5  = lane >> 5;

    // ---- XCD-locality check (one-time, system-scope => placement-safe) ----
    {
        int xcc = 0;
        asm volatile("s_getreg_b32 %0, hwreg(HW_REG_XCC_ID)" : "=s"(xcc));
        if (tid == 0) {
            __hip_atomic_store(&xflag[grp * 32 + w], xcc + 1, __ATOMIC_RELAXED,
                               __HIP_MEMORY_SCOPE_SYSTEM);
        }
        if (wv == 0) {
            int v;
            for (;;) {
                v = __hip_atomic_load(&xflag[grp * 32 + (lane & 31)], __ATOMIC_RELAXED,
                                      __HIP_MEMORY_SCOPE_SYSTEM);
                if (__all(v != 0)) break;
                __builtin_amdgcn_s_sleep(2);
            }
            int v0 = __shfl(v, 0, 64);
            if (lane == 0) use_local_sh = __all(v == v0) ? 1 : 0;
        }
    }

    // one-time: B fragments for both gates of the pair (128 regs/lane total)
    bf16x8 Bf0[16], Bf1[16];
    {
        const unsigned short* wb0 = Wt + (size_t)(((w * 4 + 2 * pv + 0) * 4 + qv) * 16) * 512
                                       + (size_t)lane * 8;
        const unsigned short* wb1 = Wt + (size_t)(((w * 4 + 2 * pv + 1) * 4 + qv) * 16) * 512
                                       + (size_t)lane * 8;
        #pragma unroll
        for (int i = 0; i < 16; ++i) {
            Bf0[i] = *(const bf16x8*)(wb0 + i * 512);
            Bf1[i] = *(const bf16x8*)(wb1 + i * 512);
        }
    }
    // one-time: XW slice into LDS
    if (tid < 384) {
        int tok = tid >> 7, g = (tid >> 5) & 3, jl = tid & 31;
        xwl[tid] = XW[(tok * 4 + g) * HID + w * 32 + jl];
    }
    // one-time: token table, 2-bit packed
    for (int i = tid; i < 4096; i += 512) {
        int row = i >> 7, b = i & 127;
        const int* xr = &x[(grp * 32 + row) * T_SEQ + b * 4];
        xtokp[i] = (unsigned char)((xr[0] & 3) | ((xr[1] & 3) << 2)
                                   | ((xr[2] & 3) << 4) | ((xr[3] & 3) << 6));
    }
    if (tid < 4) qctr[tid] = 0;
    __syncthreads();
    const bool use_local = (use_local_sh != 0);

    // elementwise ownership: thread -> row = tid>>4, cols jc2*2..+2
    const int erow = tid >> 4;
    const int jc2  = tid & 15;
    float cst[2] = {0.f, 0.f};
    unsigned long long* hs64 = (unsigned long long*)hs;

    for (int s = 0; s < T_SEQ; ++s) {
        // ---- wave-level wait: only this quarter's 8 producers ----
        if (s > 0) {
            const int fidx = grp * 32 + qv * 8 + (lane & 7);
            if (use_local) {
                for (;;) {
                    int v = __hip_atomic_load(&flags[fidx], __ATOMIC_RELAXED,
                                              __HIP_MEMORY_SCOPE_AGENT);
                    if (__all(v >= s)) break;
                    __builtin_amdgcn_s_sleep(1);
                }
            } else {
                for (;;) {
                    int v = __hip_atomic_load(&flags[fidx], __ATOMIC_RELAXED,
                                              __HIP_MEMORY_SCOPE_SYSTEM);
                    if (__all(v >= s)) break;
                    __builtin_amdgcn_s_sleep(1);
                }
            }
        }

        // ---- stage own half (16 rows) of quarter slice: 8 KB/wave ----
        {
            const unsigned long long* hp64 = (const unsigned long long*)
                (hbuf32 + (size_t)(s & 1) * (BATCH * HID / 2));
            unsigned long long tmp[16];
            #pragma unroll
            for (int it = 0; it < 16; ++it) {
                int flat = it * 64 + lane;           // 1024 qwords/wave
                int row  = pv * 16 + (flat >> 6);
                int c4   = flat & 63;
                const unsigned long long* src =
                    &hp64[(size_t)(grp * 32 + row) * 256 + qv * 64 + c4];
                tmp[it] = use_local
                    ? __hip_atomic_load(src, __ATOMIC_RELAXED, __HIP_MEMORY_SCOPE_AGENT)
                    : __hip_atomic_load(src, __ATOMIC_RELAXED, __HIP_MEMORY_SCOPE_SYSTEM);
            }
            #pragma unroll
            for (int it = 0; it < 16; ++it) {
                int flat = it * 64 + lane;
                int row  = pv * 16 + (flat >> 6);
                int c4   = flat & 63;
                hs64[qv * 2112 + row * 66 + c4] = tmp[it];
            }
        }
        // ---- team barrier (2 waves of this quarter) ----
        {
            if (lane == 0)
                __hip_atomic_fetch_add(&qctr[qv], 1, __ATOMIC_ACQ_REL,
                                       __HIP_MEMORY_SCOPE_WORKGROUP);
            const int target = 2 * (s + 1);
            while (__hip_atomic_load(&qctr[qv], __ATOMIC_ACQUIRE,
                                     __HIP_MEMORY_SCOPE_WORKGROUP) < target)
                __builtin_amdgcn_s_sleep(0);
        }

        // ---- GEMM: 2 gates x 32x32 tile over this K-quarter ----
        floatx16 acc0 = {0.f,0.f,0.f,0.f,0.f,0.f,0.f,0.f,0.f,0.f,0.f,0.f,0.f,0.f,0.f,0.f};
        floatx16 acc1 = acc0;
        const unsigned short* ap = hs + qv * 8448 + m32 * 264 + hv5 * 8;
        #pragma unroll
        for (int i = 0; i < 16; ++i) {
            bf16x8 a = *(const bf16x8*)(ap + i * 16);
            acc0 = __builtin_amdgcn_mfma_f32_32x32x16_bf16(a, Bf0[i], acc0, 0, 0, 0);
            acc1 = __builtin_amdgcn_mfma_f32_32x32x16_bf16(a, Bf1[i], acc1, 0, 0, 0);
        }

        // ---- scatter C (col=lane&31, row=(reg&3)+8*(reg>>2)+4*(lane>>5)) ----
        {
            float* gb0 = &gbuf[(size_t)((2 * pv + 0) * 4 + qv) * 1152];
            float* gb1 = &gbuf[(size_t)((2 * pv + 1) * 4 + qv) * 1152];
            #pragma unroll
            for (int reg = 0; reg < 16; ++reg) {
                int row = (reg & 3) + 8 * (reg >> 2) + 4 * hv5;
                gb0[row * 36 + m32] = acc0[reg];
                gb1[row * 36 + m32] = acc1[reg];
            }
        }
        __syncthreads();   // all 16 partial tiles ready

        // ---- elementwise LSTM cell update, h(s+1) out ----
        {
            int byte = xtokp[erow * 128 + (s >> 2)];
            int tk   = (byte >> ((s & 3) * 2)) & 3;
            const float* xb = &xwl[tk * 128];
            const int go = erow * 36 + jc2 * 2;
            floatx2 ag, ai, af, ao;
            #define SUMQ(dst, g) dst = *(const floatx2*)&gbuf[((g)*4+0)*1152 + go] \
                                     + *(const floatx2*)&gbuf[((g)*4+1)*1152 + go] \
                                     + *(const floatx2*)&gbuf[((g)*4+2)*1152 + go] \
                                     + *(const floatx2*)&gbuf[((g)*4+3)*1152 + go]
            SUMQ(ag, 0); SUMQ(ai, 1); SUMQ(af, 2); SUMQ(ao, 3);
            #undef SUMQ
            floatx2 xg = *(const floatx2*)&xb[0 * 32 + jc2 * 2];
            floatx2 xi = *(const floatx2*)&xb[1 * 32 + jc2 * 2];
            floatx2 xf = *(const floatx2*)&xb[2 * 32 + jc2 * 2];
            floatx2 xo = *(const floatx2*)&xb[3 * 32 + jc2 * 2];
            unsigned int hvv[2];
            #pragma unroll
            for (int u = 0; u < 2; ++u) {
                float g  = tanh_fast(ag[u] + xg[u]);
                float ii = sig_fast(ai[u] + xi[u]);
                float ff = sig_fast(af[u] + xf[u]);
                float oo = sig_fast(ao[u] + xo[u]);
                float cn = g * ii + cst[u] * ff;
                float h  = tanh_fast(cn) * oo;
                cst[u]   = (tk != 0) ? cn : 0.0f;   // pad = ((x+1)//2) in {0,1,1}
                hvv[u]   = f2bf(h);
            }
            unsigned int* hnext = hbuf32 + (size_t)((s + 1) & 1) * (BATCH * HID / 2);
            unsigned int* hp = &hnext[((grp * 32 + erow) * HID + w * 32 + jc2 * 2) >> 1];
            unsigned int hval = hvv[0] | (hvv[1] << 16);
            if (use_local) {
                __hip_atomic_store(hp, hval, __ATOMIC_RELAXED, __HIP_MEMORY_SCOPE_WORKGROUP);
            } else {
                __hip_atomic_store(hp, hval, __ATOMIC_RELAXED, __HIP_MEMORY_SCOPE_SYSTEM);
            }
        }
        // drains vmcnt per wave before s_barrier => all h stores complete at
        // their coherence point before the flag is published
        __syncthreads();

        if (s < T_SEQ - 1 && tid == 0) {
            if (use_local) {
                __hip_atomic_store(&flags[grp * 32 + w], s + 1,
                                   __ATOMIC_RELAXED, __HIP_MEMORY_SCOPE_WORKGROUP);
            } else {
                __hip_atomic_store(&flags[grp * 32 + w], s + 1,
                                   __ATOMIC_RELAXED, __HIP_MEMORY_SCOPE_SYSTEM);
            }
        }
    }
}

// -------------------- projection + log_softmax over batch dim ---------------
__global__ void proj_kernel(const unsigned short* __restrict__ h,
                            const float* __restrict__ wph, const float* __restrict__ bp,
                            float* __restrict__ out) {
    __shared__ float wl[HID * NCLS];
    __shared__ float red[256];
    int tid = threadIdx.x;      // = batch row
    for (int i = tid; i < HID * NCLS; i += 256) wl[i] = wph[i];
    __syncthreads();
    float p[NCLS];
    #pragma unroll
    for (int c2 = 0; c2 < NCLS; ++c2) p[c2] = bp[c2];
    const unsigned short* hr = h + tid * HID;
    for (int k0 = 0; k0 < HID / 8; ++k0) {
        bf16x8 hv = *(const bf16x8*)(hr + k0 * 8);
        #pragma unroll
        for (int j = 0; j < 8; ++j) {
            float hk = (float)hv[j];
            #pragma unroll
            for (int c2 = 0; c2 < NCLS; ++c2) p[c2] += hk * wl[(k0 * 8 + j) * NCLS + c2];
        }
    }
    for (int c2 = 0; c2 < NCLS; ++c2) {
        red[tid] = p[c2];
        __syncthreads();
        for (int s = 128; s > 0; s >>= 1) {
            if (tid < s) red[tid] = fmaxf(red[tid], red[tid + s]);
            __syncthreads();
        }
        float mx = red[0];
        __syncthreads();
        red[tid] = __expf(p[c2] - mx);
        __syncthreads();
        for (int s = 128; s > 0; s >>= 1) {
            if (tid < s) red[tid] += red[tid + s];
            __syncthreads();
        }
        float lse = mx + __logf(red[0]);
        __syncthreads();
        out[tid * NCLS + c2] = p[c2] - lse;
    }
}

// ----------------------------------------------------------------------------
extern "C" void kernel_launch(void* const* d_in, const int* in_sizes, int n_in,
                              void* d_out, int out_size, void* d_ws, size_t ws_size,
                              hipStream_t stream) {
    const int*   x    = (const int*)d_in[0];
    const float* emb  = (const float*)d_in[1];
    const float* wgx  = (const float*)d_in[2];
    const float* wgh  = (const float*)d_in[3];
    const float* bg_  = (const float*)d_in[4];
    const float* wix  = (const float*)d_in[5];
    const float* wih  = (const float*)d_in[6];
    const float* bi_  = (const float*)d_in[7];
    const float* wfx  = (const float*)d_in[8];
    const float* wfh  = (const float*)d_in[9];
    const float* bf_  = (const float*)d_in[10];
    const float* wox  = (const float*)d_in[11];
    const float* woh  = (const float*)d_in[12];
    const float* bo_  = (const float*)d_in[13];
    const float* wph  = (const float*)d_in[14];
    const float* bp_  = (const float*)d_in[15];
    float* out = (float*)d_out;

    char* wsp = (char*)d_ws;
    int*            flags = (int*)wsp;                                      // 4 KB
    int*            xflag = (int*)(wsp + 4096);                             // 4 KB
    float*          XW    = (float*)(wsp + 8192);                           // 48 KB
    unsigned short* Wt    = (unsigned short*)(wsp + 8192 + 49152);          // 8 MB
    unsigned int*   hbuf32= (unsigned int*)(wsp + 8192 + 49152 + 8388608);  // 1 MB

    hipMemsetAsync(flags, 0, 8192, stream);                                  // flags+xflag
    hipMemsetAsync(hbuf32, 0, BATCH * HID * sizeof(unsigned short), stream); // h0 = 0

    prep_xw_kernel<<<48, 256, 0, stream>>>(emb, wgx, wix, wfx, wox,
                                           bg_, bi_, bf_, bo_, XW);
    prep_w_kernel<<<8192, 64, 0, stream>>>(wgh, wih, wfh, woh, Wt);

    void* args[] = { (void*)&x, (void*)&XW, (void*)&Wt, (void*)&hbuf32,
                     (void*)&flags, (void*)&xflag };
    hipError_t cerr = hipLaunchCooperativeKernel((void*)lstm_kernel, dim3(256), dim3(512),
                                                 args, 0, stream);
    if (cerr != hipSuccess) {
        // Fallback: plain launch. The flag protocol needs only co-residency,
        // which grid=256 at 1 WG/CU provides.
        lstm_kernel<<<dim3(256), dim3(512), 0, stream>>>(x, XW, Wt, hbuf32, flags, xflag);
    }

    proj_kernel<<<1, 256, 0, stream>>>((const unsigned short*)hbuf32, wph, bp_, out);
}